// Round 5
// baseline (1335.361 us; speedup 1.0000x reference)
//
#include <hip/hip_runtime.h>
#include <hip/hip_bf16.h>

typedef __bf16 bf16x8 __attribute__((ext_vector_type(8)));
typedef float  f32x4  __attribute__((ext_vector_type(4)));

#define DIM    512
#define DINNER 1024
#define SEQL   256
#define BATCH  2
#define NLAYER 7    // layer 7's mixer output is discarded by the reference
#define NCH    8    // scan chunks
#define CLEN   32   // steps per chunk
#define NBLK   256  // == CU count; 127.7KB LDS forces 1 block/CU -> all co-resident
#define NTHR   1024

#define N4WI (NLAYER * 2048 * 512 / 4)
#define N4WX (NLAYER * 64 * 1024 / 4)
#define N4WO (NLAYER * 512 * 1024 / 4)
#define N4WD (NLAYER * 1024 * 32 / 4)
#define N4ALL (N4WI + N4WX + N4WO + N4WD)

// ---------------- two-level tree barrier, read-only polling ----------------
// Per barrier instance: 1024B. group counters at +0..+448 (64B apart),
// root at +512, release flag at +576. All counters fresh (memset per launch).
__device__ __forceinline__ void gridbar(unsigned* bar) {
  __syncthreads();
  if (threadIdx.x == 0) {
    __threadfence();   // release: agent-scope fence (flush L1, order writes)
    unsigned g = __hip_atomic_fetch_add(bar + (blockIdx.x & 7) * 16, 1u,
                                        __ATOMIC_RELAXED, __HIP_MEMORY_SCOPE_AGENT);
    if (g == 31u) {    // last of my 32-block group
      unsigned r = __hip_atomic_fetch_add(bar + 128, 1u,
                                          __ATOMIC_RELAXED, __HIP_MEMORY_SCOPE_AGENT);
      if (r == 7u)     // last group: release
        __hip_atomic_store(bar + 144, 1u, __ATOMIC_RELEASE, __HIP_MEMORY_SCOPE_AGENT);
    }
    while (__hip_atomic_load(bar + 144, __ATOMIC_ACQUIRE, __HIP_MEMORY_SCOPE_AGENT) == 0u)
      __builtin_amdgcn_s_sleep(4);
    __threadfence();   // acquire: invalidate L1 for fresh reads
  }
  __syncthreads();
}

// ---- 32x32 quadrant GEMM over a K-range: acc += A[row0..+32,k] * B[col0..+32,k]^T
__device__ __forceinline__ void qgemm32(const __hip_bfloat16* __restrict__ A,
                                        const __hip_bfloat16* __restrict__ B,
                                        int K, int row0, int col0, int kc0, int nkc,
                                        int lane, f32x4 acc[4]) {
  const int r = lane & 15, g = lane >> 4;
  const bf16x8* pa0 = reinterpret_cast<const bf16x8*>(A + (size_t)(row0 + r) * K) + g + kc0 * 4;
  const bf16x8* pa1 = reinterpret_cast<const bf16x8*>(A + (size_t)(row0 + 16 + r) * K) + g + kc0 * 4;
  const bf16x8* pb0 = reinterpret_cast<const bf16x8*>(B + (size_t)(col0 + r) * K) + g + kc0 * 4;
  const bf16x8* pb1 = reinterpret_cast<const bf16x8*>(B + (size_t)(col0 + 16 + r) * K) + g + kc0 * 4;
#pragma unroll 2
  for (int kc = 0; kc < nkc; ++kc) {
    bf16x8 a0 = pa0[kc * 4];
    bf16x8 a1 = pa1[kc * 4];
    bf16x8 b0 = pb0[kc * 4];
    bf16x8 b1 = pb1[kc * 4];
    acc[0] = __builtin_amdgcn_mfma_f32_16x16x32_bf16(a0, b0, acc[0], 0, 0, 0);
    acc[1] = __builtin_amdgcn_mfma_f32_16x16x32_bf16(a0, b1, acc[1], 0, 0, 0);
    acc[2] = __builtin_amdgcn_mfma_f32_16x16x32_bf16(a1, b0, acc[2], 0, 0, 0);
    acc[3] = __builtin_amdgcn_mfma_f32_16x16x32_bf16(a1, b1, acc[3], 0, 0, 0);
  }
}

#define SMEM_BYTES 127744

__global__ __launch_bounds__(NTHR) void k_mega(
    const float* __restrict__ x,   const float* __restrict__ Wi,
    const float* __restrict__ cw,  const float* __restrict__ cb,
    const float* __restrict__ Wx,  const float* __restrict__ Wdt,
    const float* __restrict__ bdt, const float* __restrict__ Alog,
    const float* __restrict__ Dv,  const float* __restrict__ Wo,
    const float* __restrict__ nw,
    float* __restrict__ res,  float* __restrict__ zbuf,
    float* __restrict__ xc,   __hip_bfloat16* __restrict__ xcb,
    float* __restrict__ dtg,  float* __restrict__ dblBC,
    __hip_bfloat16* __restrict__ y,
    __hip_bfloat16* __restrict__ wib, __hip_bfloat16* __restrict__ wxb,
    __hip_bfloat16* __restrict__ wob, __hip_bfloat16* __restrict__ wdtb,
    unsigned* __restrict__ bars, float* __restrict__ out) {
  __shared__ __align__(16) char smem[SMEM_BYTES];

  const int tid = threadIdx.x;
  const int bid = blockIdx.x;
  const int wid = tid >> 6;
  const int lane = tid & 63;
  const int r = lane & 15, g = lane >> 4;
  unsigned* bar = bars;

  // ================= S0: weight casts (f32->bf16) + input transpose =============
  for (int i = bid * NTHR + tid; i < N4ALL; i += NBLK * NTHR) {
    const float* src; __hip_bfloat16* dst; int j;
    if (i < N4WI)                    { src = Wi;  dst = wib;  j = i; }
    else if (i < N4WI + N4WX)        { src = Wx;  dst = wxb;  j = i - N4WI; }
    else if (i < N4WI + N4WX + N4WO) { src = Wo;  dst = wob;  j = i - N4WI - N4WX; }
    else                             { src = Wdt; dst = wdtb; j = i - N4WI - N4WX - N4WO; }
    float4 v = reinterpret_cast<const float4*>(src)[j];
    struct alignas(8) B4 { __hip_bfloat16 a, b, c, d; };
    B4 o{ (__hip_bfloat16)v.x, (__hip_bfloat16)v.y, (__hip_bfloat16)v.z, (__hip_bfloat16)v.w };
    reinterpret_cast<B4*>(dst)[j] = o;
  }
  {
    int idx = bid * NTHR + tid;             // 262144 = B*L*DIM exactly
    int d = idx & (DIM - 1), l = (idx >> 9) & (SEQL - 1), b = idx >> 17;
    res[idx] = x[((size_t)((b << 9) + d) << 8) + l];
  }
  gridbar(bar); bar += 256;

  for (int L = 0; L < NLAYER; ++L) {
    const __hip_bfloat16* wiL = wib + (size_t)L * 2048 * 512;
    const __hip_bfloat16* wxL = wxb + (size_t)L * 64 * 1024;
    const __hip_bfloat16* woL = wob + (size_t)L * 512 * 1024;
    const __hip_bfloat16* wdL = wdtb + (size_t)L * 1024 * 32;
    const float* bdtL = bdt + L * DINNER;
    const float* alog = Alog + (size_t)L * DINNER * 16;
    const float* dv   = Dv + L * DINNER;
    const float* nwL  = nw + L * DIM;
    const float4* cwL = reinterpret_cast<const float4*>(cw) + (size_t)L * DINNER;
    const float* cbL  = cb + L * DINNER;

    // ========== STAGE 1: rmsnorm + in_proj (48x128 tile) + conv + silu ==========
    // 256 blocks: ttile = bid>>4 (16 x 32 tokens), sl = bid&15 (16 x 64 cols).
    // Block computes xz for rows t0-3..t0+44 (3-row conv halo, redundant) x
    // {xc cols [64sl,64sl+64), z cols [1024+64sl,+64)} entirely in LDS.
    {
      __hip_bfloat16 (*s_hn)[520] = (__hip_bfloat16(*)[520])smem;       // 49920B
      float (*s_xz)[132] = (float(*)[132])(smem + 49920);               // 25344B
      const int ttile = bid >> 4, sl = bid & 15;
      const int t0 = ttile * 32, m0 = t0 - 3;
      // rmsnorm: 3 rows per wave (48 rows incl. halo + rounding)
#pragma unroll
      for (int k = 0; k < 3; ++k) {
        int rw = wid * 3 + k;
        int gr = m0 + rw;
        int grc = min(max(gr, 0), 511);
        const float* rr = res + ((size_t)grc << 9);
        float v[8]; float ssum = 0.f;
#pragma unroll
        for (int j2 = 0; j2 < 8; ++j2) { v[j2] = rr[lane + (j2 << 6)]; ssum = fmaf(v[j2], v[j2], ssum); }
#pragma unroll
        for (int m = 1; m < 64; m <<= 1) ssum += __shfl_xor(ssum, m);
        float inv = rsqrtf(ssum * (1.0f / 512.0f) + 1e-5f);
#pragma unroll
        for (int j2 = 0; j2 < 8; ++j2)
          s_hn[rw][lane + (j2 << 6)] = (__hip_bfloat16)(v[j2] * inv * nwL[lane + (j2 << 6)]);
      }
      __syncthreads();
      // in_proj: 24 jobs (3 M-frags x 8 col-frags), waves take j=wid, wid+16
      for (int j = wid; j < 24; j += 16) {
        int mf = j >> 3, cf = j & 7;
        int gcol = (cf < 4) ? (sl * 64 + cf * 16 + r) : (1024 + sl * 64 + (cf - 4) * 16 + r);
        const bf16x8* pb = reinterpret_cast<const bf16x8*>(wiL + (size_t)gcol * 512) + g;
        f32x4 acc = {0.f, 0.f, 0.f, 0.f};
#pragma unroll
        for (int kc = 0; kc < 16; ++kc) {
          bf16x8 a = *reinterpret_cast<const bf16x8*>(&s_hn[mf * 16 + r][kc * 32 + g * 8]);
          acc = __builtin_amdgcn_mfma_f32_16x16x32_bf16(a, pb[kc * 4], acc, 0, 0, 0);
        }
        int cc = (cf < 4) ? (cf * 16 + r) : (64 + (cf - 4) * 16 + r);
#pragma unroll
        for (int jj = 0; jj < 4; ++jj) s_xz[mf * 16 + g * 4 + jj][cc] = acc[jj];
      }
      __syncthreads();
      // conv + silu + writes (xc f32, xcb bf16, z f32); 2 els/thread
      const int t0s = t0 & 255;
#pragma unroll
      for (int k = 0; k < 2; ++k) {
        int e = tid + (k << 10);            // 2048 = 32 rows x 64 cols
        int lloc = e >> 6, c = e & 63;
        int gd = sl * 64 + c;
        int token = t0 + lloc;
        int lseq = t0s + lloc;
        float4 wv = cwL[gd];
        float accv = cbL[gd];
        accv = fmaf(s_xz[lloc + 3][c], wv.w, accv);
        if (lseq >= 1) accv = fmaf(s_xz[lloc + 2][c], wv.z, accv);
        if (lseq >= 2) accv = fmaf(s_xz[lloc + 1][c], wv.y, accv);
        if (lseq >= 3) accv = fmaf(s_xz[lloc + 0][c], wv.x, accv);
        float sv = accv / (1.f + __expf(-accv));
        size_t o = (size_t)token * 1024 + gd;
        xc[o] = sv;
        xcb[o] = (__hip_bfloat16)sv;
        zbuf[o] = s_xz[lloc + 3][64 + c];
      }
    }
    gridbar(bar); bar += 256;

    // ========== STAGE 2: x_proj (split-K) + dt_proj MFMA + softplus =============
    // 32 blocks x 16 tokens. dbl[16][64] reduced in LDS; cols 32..64 -> dblBC;
    // cols 0..32 -> bf16 -> dt MFMA (K=32) -> +bias -> softplus -> dtg.
    if (bid < 32) {
      float* s_red = (float*)smem;                        // [4][16][68] = 17408B
      __hip_bfloat16 (*s_dblb)[40] = (__hip_bfloat16(*)[40])(smem + 17408);  // 1280B
      const int t0 = bid * 16;
      {
        int nf = wid >> 2, ks = wid & 3;
        const bf16x8* pa = reinterpret_cast<const bf16x8*>(xcb + (size_t)(t0 + r) * 1024) + ks * 32 + g;
        const bf16x8* pb = reinterpret_cast<const bf16x8*>(wxL + (size_t)(nf * 16 + r) * 1024) + ks * 32 + g;
        f32x4 acc = {0.f, 0.f, 0.f, 0.f};
#pragma unroll
        for (int kc = 0; kc < 8; ++kc)
          acc = __builtin_amdgcn_mfma_f32_16x16x32_bf16(pa[kc * 4], pb[kc * 4], acc, 0, 0, 0);
#pragma unroll
        for (int jj = 0; jj < 4; ++jj)
          s_red[ks * 1088 + (g * 4 + jj) * 68 + nf * 16 + r] = acc[jj];
      }
      __syncthreads();
      {
        int row = tid >> 6, col = tid & 63;               // 1024 = 16x64
        float dsum = s_red[row * 68 + col] + s_red[1088 + row * 68 + col]
                   + s_red[2176 + row * 68 + col] + s_red[3264 + row * 68 + col];
        if (col >= 32) dblBC[(size_t)(t0 + row) * 32 + (col - 32)] = dsum;
        else           s_dblb[row][col] = (__hip_bfloat16)dsum;
      }
      __syncthreads();
      {
        bf16x8 a = *reinterpret_cast<const bf16x8*>(&s_dblb[r][g * 8]);
#pragma unroll
        for (int q = 0; q < 4; ++q) {
          int dch = (wid * 4 + q) * 16 + r;
          bf16x8 b = *reinterpret_cast<const bf16x8*>(wdL + (size_t)dch * 32 + g * 8);
          f32x4 acc = {0.f, 0.f, 0.f, 0.f};
          acc = __builtin_amdgcn_mfma_f32_16x16x32_bf16(a, b, acc, 0, 0, 0);
          float bsv = bdtL[dch];
#pragma unroll
          for (int jj = 0; jj < 4; ++jj) {
            float draw = acc[jj] + bsv;
            dtg[(size_t)(t0 + g * 4 + jj) * 1024 + dch] =
                (draw > 20.f) ? draw : log1pf(__expf(draw));
          }
        }
      }
    }
    gridbar(bar); bar += 256;

    // ========== STAGE 3: selective scan (chunked two-pass, verified body) =======
    {
      float (*s_dt)[260] = (float(*)[260])(smem);
      float (*s_xc)[260] = (float(*)[260])(smem + 8320);
      float (*s_B)[260]  = (float(*)[260])(smem + 16640);
      float (*s_C)[260]  = (float(*)[260])(smem + 33280);
      float (*s_cp)[68]  = (float(*)[68]) (smem + 49920);
      float (*s_pe)[128] = (float(*)[128])(smem + 119552);
      float (*s_se)[128] = (float(*)[128])(smem + 123648);
      const int cg = tid >> 7;
      const int tt = tid & 127;
      const int n = tt & 15, dl = tt >> 4;
      const int b = bid >> 7;
      const int d0 = (bid & 127) << 3;
      const int d = d0 + dl;
      const int bL = b * SEQL;
#pragma unroll
      for (int k = 0; k < 4; ++k) {
        int idx = tid + (k << 10);          // 4096 = 256 x 16
        int l = idx >> 4, nn = idx & 15;
        const float* rowp = dblBC + ((size_t)(bL + l) << 5);
        s_B[nn][l] = rowp[nn];
        s_C[nn][l] = rowp[16 + nn];
      }
#pragma unroll
      for (int k = 0; k < 2; ++k) {
        int idx = tid + (k << 10);          // 2048 = 256 x 8
        int l = idx >> 3, dd = idx & 7;
        size_t o = ((size_t)(bL + l) << 10) + d0 + dd;
        s_xc[dd][l] = xc[o];
        s_dt[dd][l] = dtg[o];
      }
      __syncthreads();

      const float An = -__expf(alog[(size_t)d * 16 + n]);
      const int lb = cg << 5;

      float s = 0.f, P = 1.f;
#pragma unroll 2
      for (int l4 = 0; l4 < CLEN; l4 += 4) {
        const int l = lb + l4;
        float4 dt4 = *reinterpret_cast<const float4*>(&s_dt[dl][l]);
        float4 xc4 = *reinterpret_cast<const float4*>(&s_xc[dl][l]);
        float4 B4  = *reinterpret_cast<const float4*>(&s_B[n][l]);
        float dA;
        dA = __expf(dt4.x * An); P *= dA; s = fmaf(dA, s, dt4.x * xc4.x * B4.x);
        dA = __expf(dt4.y * An); P *= dA; s = fmaf(dA, s, dt4.y * xc4.y * B4.y);
        dA = __expf(dt4.z * An); P *= dA; s = fmaf(dA, s, dt4.z * xc4.z * B4.z);
        dA = __expf(dt4.w * An); P *= dA; s = fmaf(dA, s, dt4.w * xc4.w * B4.w);
      }
      s_pe[cg][tt] = P;
      s_se[cg][tt] = s;
      __syncthreads();

      float ss = 0.f;
      for (int c = 0; c < cg; ++c) ss = fmaf(s_pe[c][tt], ss, s_se[c][tt]);

      float s2 = ss;
#pragma unroll 2
      for (int l4 = 0; l4 < CLEN; l4 += 4) {
        const int l = lb + l4;
        float4 dt4 = *reinterpret_cast<const float4*>(&s_dt[dl][l]);
        float4 xc4 = *reinterpret_cast<const float4*>(&s_xc[dl][l]);
        float4 B4  = *reinterpret_cast<const float4*>(&s_B[n][l]);
        float4 C4  = *reinterpret_cast<const float4*>(&s_C[n][l]);
        float dA, c;
        dA = __expf(dt4.x * An); s2 = fmaf(dA, s2, dt4.x * xc4.x * B4.x); c = s2 * C4.x;
        c += __shfl_xor(c, 1); if (!(n & 1)) s_cp[l + 0][(dl << 3) | (n >> 1)] = c;
        dA = __expf(dt4.y * An); s2 = fmaf(dA, s2, dt4.y * xc4.y * B4.y); c = s2 * C4.y;
        c += __shfl_xor(c, 1); if (!(n & 1)) s_cp[l + 1][(dl << 3) | (n >> 1)] = c;
        dA = __expf(dt4.z * An); s2 = fmaf(dA, s2, dt4.z * xc4.z * B4.z); c = s2 * C4.z;
        c += __shfl_xor(c, 1); if (!(n & 1)) s_cp[l + 2][(dl << 3) | (n >> 1)] = c;
        dA = __expf(dt4.w * An); s2 = fmaf(dA, s2, dt4.w * xc4.w * B4.w); c = s2 * C4.w;
        c += __shfl_xor(c, 1); if (!(n & 1)) s_cp[l + 3][(dl << 3) | (n >> 1)] = c;
      }
      __syncthreads();

#pragma unroll
      for (int k = 0; k < 2; ++k) {
        int idx = tid + (k << 10);
        int l = idx >> 3, dd = idx & 7;
        const float* cr = &s_cp[l][dd << 3];
        float4 a0 = *reinterpret_cast<const float4*>(cr);
        float4 a1 = *reinterpret_cast<const float4*>(cr + 4);
        float sum = ((a0.x + a0.y) + (a0.z + a0.w)) + ((a1.x + a1.y) + (a1.z + a1.w));
        float xcv = s_xc[dd][l];
        float zv = zbuf[((size_t)(bL + l) << 10) + d0 + dd];
        float yv = (sum + dv[d0 + dd] * xcv) * (zv / (1.f + __expf(-zv)));
        y[((size_t)(bL + l) << 10) + d0 + dd] = (__hip_bfloat16)yv;
      }
    }
    gridbar(bar); bar += 256;

    // ========== STAGE 4: out_proj (+residual), 16-way in-block split-K ==========
    {
      float* s_red = (float*)smem;                        // [16][32][34] = 69632B
      int tile = bid >> 2, q = bid & 3;
      int row0 = (tile >> 3) * 64 + ((q >> 1) << 5);
      int col0 = (tile & 7) * 64 + ((q & 1) << 5);
      f32x4 zz = {0.f, 0.f, 0.f, 0.f};
      f32x4 acc[4] = {zz, zz, zz, zz};
      qgemm32(y, woL, 1024, row0, col0, wid * 2, 2, lane, acc);
      float* sr = s_red + wid * 1088;
#pragma unroll
      for (int e = 0; e < 4; ++e)
#pragma unroll
        for (int jj = 0; jj < 4; ++jj)
          sr[(((e >> 1) << 4) + (g << 2) + jj) * 34 + ((e & 1) << 4) + r] = acc[e][jj];
      __syncthreads();
      {
        int rrow = tid >> 5, rcol = tid & 31;
        float sum = 0.f;
#pragma unroll
        for (int w = 0; w < 16; ++w) sum += s_red[w * 1088 + rrow * 34 + rcol];
        res[(size_t)(row0 + rrow) * 512 + col0 + rcol] += sum;
      }
    }
    gridbar(bar); bar += 256;
  }

  // ================= final: out[b][c][l] = res[b][l][c] =================
  {
    int idx = bid * NTHR + tid;             // 262144
    int l = idx & (SEQL - 1), c = (idx >> 8) & (DIM - 1), b = idx >> 17;
    out[idx] = res[((size_t)((b << 8) + l) << 9) + c];
  }
}

// ---------------- launcher ----------------
extern "C" void kernel_launch(void* const* d_in, const int* in_sizes, int n_in,
                              void* d_out, int out_size, void* d_ws, size_t ws_size,
                              hipStream_t stream) {
  (void)in_sizes; (void)n_in; (void)out_size; (void)ws_size;
  const float* x    = (const float*)d_in[0];
  const float* Wi   = (const float*)d_in[1];
  const float* cw   = (const float*)d_in[2];
  const float* cb   = (const float*)d_in[3];
  const float* Wx   = (const float*)d_in[4];
  const float* Wdt  = (const float*)d_in[5];
  const float* bdt  = (const float*)d_in[6];
  const float* Alog = (const float*)d_in[7];
  const float* Dv   = (const float*)d_in[8];
  const float* Wo   = (const float*)d_in[9];
  const float* nw   = (const float*)d_in[10];

  char* ws = (char*)d_ws;
  float*          res   = (float*)(ws + 0);                 // 1 MB
  float*          zbuf  = (float*)(ws + 1048576);           // 2 MB
  float*          xc    = (float*)(ws + 3145728);           // 2 MB
  __hip_bfloat16* xcb   = (__hip_bfloat16*)(ws + 5242880);  // 1 MB
  float*          dtg   = (float*)(ws + 6291456);           // 2 MB
  float*          dblBC = (float*)(ws + 8388608);           // 64 KB
  __hip_bfloat16* y     = (__hip_bfloat16*)(ws + 8454144);  // 1 MB
  __hip_bfloat16* wib   = (__hip_bfloat16*)(ws + 9502720);  // 14 MB
  __hip_bfloat16* wxb   = (__hip_bfloat16*)(ws + 24182784); // 0.875 MB
  __hip_bfloat16* wob   = (__hip_bfloat16*)(ws + 25100288); // 7 MB
  __hip_bfloat16* wdtb  = (__hip_bfloat16*)(ws + 32440320); // 448 KB
  unsigned*       bars  = (unsigned*)(ws + 32899072);       // 29 x 1KB

  hipMemsetAsync(bars, 0, 32768, stream);
  k_mega<<<NBLK, NTHR, 0, stream>>>(x, Wi, cw, cb, Wx, Wdt, bdt, Alog, Dv, Wo, nw,
                                    res, zbuf, xc, xcb, dtg, dblBC, y,
                                    wib, wxb, wob, wdtb, bars, (float*)d_out);
}

// Round 6
// 399.885 us; speedup vs baseline: 3.3394x; 3.3394x over previous
//
#include <hip/hip_runtime.h>
#include <hip/hip_bf16.h>

typedef __bf16 bf16x8 __attribute__((ext_vector_type(8)));
typedef float  f32x4  __attribute__((ext_vector_type(4)));

#define DIM    512
#define DINNER 1024
#define SEQL   256
#define NLAYER 7    // layer 7's mixer output is discarded by the reference
#define LPAD   260  // [.][l] LDS row stride: 260%32==4 -> staggered banks
#define NCH    8
#define CLEN   32

#define N4WI (NLAYER * 2048 * 512 / 4)
#define N4WX (NLAYER * 64 * 1024 / 4)
#define N4WO (NLAYER * 512 * 1024 / 4)
#define N4WD (NLAYER * 1024 * 32 / 4)
#define N4ALL (N4WI + N4WX + N4WO + N4WD)   // 2,924,544 -> /256 = 11424 blocks

// ---------------- transposes ----------------
__global__ __launch_bounds__(256) void k_transpose_in(const float* __restrict__ x,
                                                      float* __restrict__ res) {
  int idx = blockIdx.x * 256 + threadIdx.x;
  int d = idx & (DIM - 1), l = (idx >> 9) & (SEQL - 1), b = idx >> 17;
  res[idx] = x[((size_t)((b << 9) + d) << 8) + l];
}
__global__ __launch_bounds__(256) void k_transpose_out(const float* __restrict__ res,
                                                       float* __restrict__ out) {
  int idx = blockIdx.x * 256 + threadIdx.x;
  int l = idx & (SEQL - 1), c = (idx >> 8) & (DIM - 1), b = idx >> 17;
  out[idx] = res[((size_t)((b << 8) + l) << 9) + c];
}

// ---------------- weight casts (4 tensors) ----------------
__global__ __launch_bounds__(256) void k_cast_all(const float* __restrict__ Wi,
                                                  const float* __restrict__ Wx,
                                                  const float* __restrict__ Wo,
                                                  const float* __restrict__ Wdt,
                                                  __hip_bfloat16* __restrict__ wib,
                                                  __hip_bfloat16* __restrict__ wxb,
                                                  __hip_bfloat16* __restrict__ wob,
                                                  __hip_bfloat16* __restrict__ wdtb) {
  int i = blockIdx.x * 256 + threadIdx.x;
  const float* src; __hip_bfloat16* dst; int j;
  if (i < N4WI)                    { src = Wi;  dst = wib;  j = i; }
  else if (i < N4WI + N4WX)        { src = Wx;  dst = wxb;  j = i - N4WI; }
  else if (i < N4WI + N4WX + N4WO) { src = Wo;  dst = wob;  j = i - N4WI - N4WX; }
  else                             { src = Wdt; dst = wdtb; j = i - N4WI - N4WX - N4WO; }
  float4 v = reinterpret_cast<const float4*>(src)[j];
  struct alignas(8) B4 { __hip_bfloat16 a, b, c, d; };
  B4 o{ (__hip_bfloat16)v.x, (__hip_bfloat16)v.y, (__hip_bfloat16)v.z, (__hip_bfloat16)v.w };
  reinterpret_cast<B4*>(dst)[j] = o;
}

// ========== k1: rmsnorm + in_proj (48x128 LDS tile) + conv + silu ==========
// 256 blocks x 1024: ttile = bid>>4 (16 x 32 tokens), sl = bid&15 (16 x 64 ch).
// Outputs: xcb[token][ch] bf16, xcT[ch][token] f32, zT[ch][token] f32.
__global__ __launch_bounds__(1024) void k_front(const float* __restrict__ res,
                                                const float* __restrict__ nwL,
                                                const __hip_bfloat16* __restrict__ wiL,
                                                const float4* __restrict__ cwL,
                                                const float* __restrict__ cbL,
                                                __hip_bfloat16* __restrict__ xcb,
                                                float* __restrict__ xcT,
                                                float* __restrict__ zT) {
  __shared__ __align__(16) char smem[75264];
  __hip_bfloat16 (*s_hn)[520] = (__hip_bfloat16(*)[520])smem;   // 48x520x2 = 49920B
  float (*s_xz)[132] = (float(*)[132])(smem + 49920);           // 48x132x4 = 25344B
  float (*s_sv)[68]  = (float(*)[68])smem;                      // aliases s_hn (after)
  const int tid = threadIdx.x, bid = blockIdx.x;
  const int wid = tid >> 6, lane = tid & 63;
  const int r = lane & 15, g = lane >> 4;
  const int ttile = bid >> 4, sl = bid & 15;
  const int t0 = ttile * 32, m0 = t0 - 3;
  // rmsnorm: 3 rows per wave (48 rows incl. 3-row conv halo)
#pragma unroll
  for (int k = 0; k < 3; ++k) {
    int rw = wid * 3 + k;
    int grc = min(max(m0 + rw, 0), 511);
    const float* rr = res + ((size_t)grc << 9);
    float v[8]; float ssum = 0.f;
#pragma unroll
    for (int j2 = 0; j2 < 8; ++j2) { v[j2] = rr[lane + (j2 << 6)]; ssum = fmaf(v[j2], v[j2], ssum); }
#pragma unroll
    for (int m = 1; m < 64; m <<= 1) ssum += __shfl_xor(ssum, m);
    float inv = rsqrtf(ssum * (1.0f / 512.0f) + 1e-5f);
#pragma unroll
    for (int j2 = 0; j2 < 8; ++j2)
      s_hn[rw][lane + (j2 << 6)] = (__hip_bfloat16)(v[j2] * inv * nwL[lane + (j2 << 6)]);
  }
  __syncthreads();
  // in_proj: 24 jobs (3 M-frags x 8 col-frags) over 16 waves
  for (int j = wid; j < 24; j += 16) {
    int mf = j >> 3, cf = j & 7;
    int gcol = (cf < 4) ? (sl * 64 + cf * 16 + r) : (1024 + sl * 64 + (cf - 4) * 16 + r);
    const bf16x8* pb = reinterpret_cast<const bf16x8*>(wiL + (size_t)gcol * 512) + g;
    f32x4 acc = {0.f, 0.f, 0.f, 0.f};
#pragma unroll
    for (int kc = 0; kc < 16; ++kc) {
      bf16x8 a = *reinterpret_cast<const bf16x8*>(&s_hn[mf * 16 + r][kc * 32 + g * 8]);
      acc = __builtin_amdgcn_mfma_f32_16x16x32_bf16(a, pb[kc * 4], acc, 0, 0, 0);
    }
    int cc = (cf < 4) ? (cf * 16 + r) : (64 + (cf - 4) * 16 + r);
#pragma unroll
    for (int jj = 0; jj < 4; ++jj) s_xz[mf * 16 + g * 4 + jj][cc] = acc[jj];
  }
  __syncthreads();
  // conv + silu; xcb store (coalesced over ch), sv stashed in LDS
  const int t0s = t0 & 255;
#pragma unroll
  for (int k = 0; k < 2; ++k) {
    int e = tid + (k << 10);               // 2048 = 32 rows x 64 cols
    int lloc = e >> 6, c = e & 63;
    int gd = sl * 64 + c;
    int lseq = t0s + lloc;
    float4 wv = cwL[gd];
    float accv = cbL[gd];
    accv = fmaf(s_xz[lloc + 3][c], wv.w, accv);
    if (lseq >= 1) accv = fmaf(s_xz[lloc + 2][c], wv.z, accv);
    if (lseq >= 2) accv = fmaf(s_xz[lloc + 1][c], wv.y, accv);
    if (lseq >= 3) accv = fmaf(s_xz[lloc + 0][c], wv.x, accv);
    float sv = accv / (1.f + __expf(-accv));
    xcb[(size_t)(t0 + lloc) * 1024 + gd] = (__hip_bfloat16)sv;
    s_sv[lloc][c] = sv;
  }
  __syncthreads();
  // transposed stores (coalesced over tokens)
#pragma unroll
  for (int k = 0; k < 2; ++k) {
    int e = tid + (k << 10);
    int lloc = e & 31, c = e >> 5;         // c in 0..63
    int gd = sl * 64 + c;
    int token = t0 + lloc;
    xcT[(size_t)gd * 512 + token] = s_sv[lloc][c];
    zT [(size_t)gd * 512 + token] = s_xz[lloc + 3][64 + c];
  }
}

// ========== k2: x_proj (4-way split-K) + dt_proj MFMA + softplus ==========
// 32 blocks x 16 tokens. Outputs: dblBC[token][32] (B|C), dtgT[ch][token].
__global__ __launch_bounds__(1024) void k_xdt(const __hip_bfloat16* __restrict__ xcb,
                                              const __hip_bfloat16* __restrict__ wxL,
                                              const __hip_bfloat16* __restrict__ wdL,
                                              const float* __restrict__ bdtL,
                                              float* __restrict__ dblBC,
                                              float* __restrict__ dtgT) {
  __shared__ __align__(16) char smem[18688];
  float* s_red = (float*)smem;                                  // [4][16][68]
  __hip_bfloat16 (*s_dblb)[40] = (__hip_bfloat16(*)[40])(smem + 17408);
  const int tid = threadIdx.x, bid = blockIdx.x;
  const int wid = tid >> 6, lane = tid & 63;
  const int r = lane & 15, g = lane >> 4;
  const int t0 = bid * 16;
  {
    int nf = wid >> 2, ks = wid & 3;
    const bf16x8* pa = reinterpret_cast<const bf16x8*>(xcb + (size_t)(t0 + r) * 1024) + ks * 32 + g;
    const bf16x8* pb = reinterpret_cast<const bf16x8*>(wxL + (size_t)(nf * 16 + r) * 1024) + ks * 32 + g;
    f32x4 acc = {0.f, 0.f, 0.f, 0.f};
#pragma unroll
    for (int kc = 0; kc < 8; ++kc)
      acc = __builtin_amdgcn_mfma_f32_16x16x32_bf16(pa[kc * 4], pb[kc * 4], acc, 0, 0, 0);
#pragma unroll
    for (int jj = 0; jj < 4; ++jj)
      s_red[ks * 1088 + (g * 4 + jj) * 68 + nf * 16 + r] = acc[jj];
  }
  __syncthreads();
  {
    int row = tid >> 6, col = tid & 63;
    float dsum = s_red[row * 68 + col] + s_red[1088 + row * 68 + col]
               + s_red[2176 + row * 68 + col] + s_red[3264 + row * 68 + col];
    if (col >= 32) dblBC[(size_t)(t0 + row) * 32 + (col - 32)] = dsum;
    else           s_dblb[row][col] = (__hip_bfloat16)dsum;
  }
  __syncthreads();
  {
    bf16x8 a = *reinterpret_cast<const bf16x8*>(&s_dblb[r][g * 8]);
#pragma unroll
    for (int q = 0; q < 4; ++q) {
      int dch = (wid * 4 + q) * 16 + r;
      bf16x8 b = *reinterpret_cast<const bf16x8*>(wdL + (size_t)dch * 32 + g * 8);
      f32x4 acc = {0.f, 0.f, 0.f, 0.f};
      acc = __builtin_amdgcn_mfma_f32_16x16x32_bf16(a, b, acc, 0, 0, 0);
      float bsv = bdtL[dch];
#pragma unroll
      for (int jj = 0; jj < 4; ++jj) {
        float draw = acc[jj] + bsv;
        dtgT[(size_t)dch * 512 + t0 + g * 4 + jj] =
            (draw > 20.f) ? draw : log1pf(__expf(draw));
      }
    }
  }
}

// ========== k3: selective scan v4 (chunked two-pass; lean coalesced prologue) ====
__global__ __launch_bounds__(1024) void k_scan(const float* __restrict__ dblBC,
                                               const float* __restrict__ dtgT,
                                               const float* __restrict__ xcT,
                                               const float* __restrict__ zT,
                                               const float* __restrict__ alog,
                                               const float* __restrict__ dv,
                                               __hip_bfloat16* __restrict__ y) {
  __shared__ __align__(16) char smem[127744];
  float (*s_dt)[LPAD] = (float(*)[LPAD])(smem);
  float (*s_xc)[LPAD] = (float(*)[LPAD])(smem + 8320);
  float (*s_B)[LPAD]  = (float(*)[LPAD])(smem + 16640);
  float (*s_C)[LPAD]  = (float(*)[LPAD])(smem + 33280);
  float (*s_cp)[68]   = (float(*)[68]) (smem + 49920);
  float (*s_pe)[128]  = (float(*)[128])(smem + 119552);
  float (*s_se)[128]  = (float(*)[128])(smem + 123648);
  const int tid = threadIdx.x, bid = blockIdx.x;
  const int cg = tid >> 7;
  const int tt = tid & 127;
  const int n = tt & 15, dl = tt >> 4;
  const int b = bid >> 7;
  const int d0 = (bid & 127) << 3;
  const int d = d0 + dl;
  const int bL = b * SEQL;

  // stage B,C from compact dblBC rows (fully coalesced float4 reads)
#pragma unroll
  for (int k = 0; k < 2; ++k) {
    int fidx = tid + (k << 10);            // 2048 float4s = 256 rows x 8
    int l = fidx >> 3, q = fidx & 7;
    float4 v = *reinterpret_cast<const float4*>(dblBC + ((size_t)(bL + l) << 5) + (q << 2));
    float* dst = (q < 4) ? &s_B[(q & 3) << 2][l] : &s_C[(q & 3) << 2][l];
    dst[0] = v.x; dst[LPAD] = v.y; dst[2 * LPAD] = v.z; dst[3 * LPAD] = v.w;
  }
  // stage dt (threads 0..511) and xc (512..1023): contiguous float4 rows
  {
    int h = tid >> 9, j = tid & 511;
    int dd = j >> 6, c4 = j & 63;
    const float* src = h ? xcT : dtgT;
    float4 v = *reinterpret_cast<const float4*>(src + (size_t)(d0 + dd) * 512 + bL + (c4 << 2));
    float (*dstA)[LPAD] = h ? s_xc : s_dt;
    *reinterpret_cast<float4*>(&dstA[dd][c4 << 2]) = v;
  }
  __syncthreads();

  const float An = -__expf(alog[(size_t)d * 16 + n]);
  const int lb = cg << 5;

  // pass 1: local scan from 0, track P = prod(dA)
  float s = 0.f, P = 1.f;
#pragma unroll 2
  for (int l4 = 0; l4 < CLEN; l4 += 4) {
    const int l = lb + l4;
    float4 dt4 = *reinterpret_cast<const float4*>(&s_dt[dl][l]);
    float4 xc4 = *reinterpret_cast<const float4*>(&s_xc[dl][l]);
    float4 B4  = *reinterpret_cast<const float4*>(&s_B[n][l]);
    float dA;
    dA = __expf(dt4.x * An); P *= dA; s = fmaf(dA, s, dt4.x * xc4.x * B4.x);
    dA = __expf(dt4.y * An); P *= dA; s = fmaf(dA, s, dt4.y * xc4.y * B4.y);
    dA = __expf(dt4.z * An); P *= dA; s = fmaf(dA, s, dt4.z * xc4.z * B4.z);
    dA = __expf(dt4.w * An); P *= dA; s = fmaf(dA, s, dt4.w * xc4.w * B4.w);
  }
  s_pe[cg][tt] = P;
  s_se[cg][tt] = s;
  __syncthreads();

  // exact chunk start state (linear recurrence)
  float ss = 0.f;
  for (int c = 0; c < cg; ++c) ss = fmaf(s_pe[c][tt], ss, s_se[c][tt]);

  // pass 2: true scan; pair-reduced partials to LDS
  float s2 = ss;
#pragma unroll 2
  for (int l4 = 0; l4 < CLEN; l4 += 4) {
    const int l = lb + l4;
    float4 dt4 = *reinterpret_cast<const float4*>(&s_dt[dl][l]);
    float4 xc4 = *reinterpret_cast<const float4*>(&s_xc[dl][l]);
    float4 B4  = *reinterpret_cast<const float4*>(&s_B[n][l]);
    float4 C4  = *reinterpret_cast<const float4*>(&s_C[n][l]);
    float dA, c;
    dA = __expf(dt4.x * An); s2 = fmaf(dA, s2, dt4.x * xc4.x * B4.x); c = s2 * C4.x;
    c += __shfl_xor(c, 1); if (!(n & 1)) s_cp[l + 0][(dl << 3) | (n >> 1)] = c;
    dA = __expf(dt4.y * An); s2 = fmaf(dA, s2, dt4.y * xc4.y * B4.y); c = s2 * C4.y;
    c += __shfl_xor(c, 1); if (!(n & 1)) s_cp[l + 1][(dl << 3) | (n >> 1)] = c;
    dA = __expf(dt4.z * An); s2 = fmaf(dA, s2, dt4.z * xc4.z * B4.z); c = s2 * C4.z;
    c += __shfl_xor(c, 1); if (!(n & 1)) s_cp[l + 2][(dl << 3) | (n >> 1)] = c;
    dA = __expf(dt4.w * An); s2 = fmaf(dA, s2, dt4.w * xc4.w * B4.w); c = s2 * C4.w;
    c += __shfl_xor(c, 1); if (!(n & 1)) s_cp[l + 3][(dl << 3) | (n >> 1)] = c;
  }
  __syncthreads();

  // epilogue: n-reduction + D*xc + silu(z) gate + store
#pragma unroll
  for (int k = 0; k < 2; ++k) {
    int idx = tid + (k << 10);
    int l = idx >> 3, dd = idx & 7;
    const float* cr = &s_cp[l][dd << 3];
    float4 a0 = *reinterpret_cast<const float4*>(cr);
    float4 a1 = *reinterpret_cast<const float4*>(cr + 4);
    float sum = ((a0.x + a0.y) + (a0.z + a0.w)) + ((a1.x + a1.y) + (a1.z + a1.w));
    float xcv = s_xc[dd][l];
    float zv = zT[(size_t)(d0 + dd) * 512 + bL + l];
    float yv = (sum + dv[d0 + dd] * xcv) * (zv / (1.f + __expf(-zv)));
    y[((size_t)(bL + l) << 10) + d0 + dd] = (__hip_bfloat16)yv;
  }
}

// ========== k4: out_proj (+residual), 256 blocks, 16-way in-block split-K ======
__global__ __launch_bounds__(1024) void k_outproj(const __hip_bfloat16* __restrict__ y,
                                                  const __hip_bfloat16* __restrict__ woL,
                                                  float* __restrict__ res) {
  __shared__ float s_red[16 * 1088];       // 69632B
  const int tid = threadIdx.x, bid = blockIdx.x;
  const int wid = tid >> 6, lane = tid & 63;
  const int r = lane & 15, g = lane >> 4;
  int tile = bid >> 2, q = bid & 3;
  int row0 = (tile >> 3) * 64 + ((q >> 1) << 5);
  int col0 = (tile & 7) * 64 + ((q & 1) << 5);
  {
    const bf16x8* pa0 = reinterpret_cast<const bf16x8*>(y + (size_t)(row0 + r) * 1024) + g + wid * 8;
    const bf16x8* pa1 = reinterpret_cast<const bf16x8*>(y + (size_t)(row0 + 16 + r) * 1024) + g + wid * 8;
    const bf16x8* pb0 = reinterpret_cast<const bf16x8*>(woL + (size_t)(col0 + r) * 1024) + g + wid * 8;
    const bf16x8* pb1 = reinterpret_cast<const bf16x8*>(woL + (size_t)(col0 + 16 + r) * 1024) + g + wid * 8;
    f32x4 zz = {0.f, 0.f, 0.f, 0.f};
    f32x4 acc[4] = {zz, zz, zz, zz};
#pragma unroll
    for (int kc = 0; kc < 2; ++kc) {
      bf16x8 a0 = pa0[kc * 4], a1 = pa1[kc * 4];
      bf16x8 b0 = pb0[kc * 4], b1 = pb1[kc * 4];
      acc[0] = __builtin_amdgcn_mfma_f32_16x16x32_bf16(a0, b0, acc[0], 0, 0, 0);
      acc[1] = __builtin_amdgcn_mfma_f32_16x16x32_bf16(a0, b1, acc[1], 0, 0, 0);
      acc[2] = __builtin_amdgcn_mfma_f32_16x16x32_bf16(a1, b0, acc[2], 0, 0, 0);
      acc[3] = __builtin_amdgcn_mfma_f32_16x16x32_bf16(a1, b1, acc[3], 0, 0, 0);
    }
    float* sr = s_red + wid * 1088;
#pragma unroll
    for (int e = 0; e < 4; ++e)
#pragma unroll
      for (int jj = 0; jj < 4; ++jj)
        sr[(((e >> 1) << 4) + (g << 2) + jj) * 34 + ((e & 1) << 4) + r] = acc[e][jj];
  }
  __syncthreads();
  {
    int rrow = tid >> 5, rcol = tid & 31;
    float sum = 0.f;
#pragma unroll
    for (int w = 0; w < 16; ++w) sum += s_red[w * 1088 + rrow * 34 + rcol];
    res[(size_t)(row0 + rrow) * 512 + col0 + rcol] += sum;
  }
}

// ---------------- launcher ----------------
extern "C" void kernel_launch(void* const* d_in, const int* in_sizes, int n_in,
                              void* d_out, int out_size, void* d_ws, size_t ws_size,
                              hipStream_t stream) {
  (void)in_sizes; (void)n_in; (void)out_size; (void)ws_size;
  const float* x    = (const float*)d_in[0];
  const float* Wi   = (const float*)d_in[1];
  const float* cw   = (const float*)d_in[2];
  const float* cb   = (const float*)d_in[3];
  const float* Wx   = (const float*)d_in[4];
  const float* Wdt  = (const float*)d_in[5];
  const float* bdt  = (const float*)d_in[6];
  const float* Alog = (const float*)d_in[7];
  const float* Dv   = (const float*)d_in[8];
  const float* Wo   = (const float*)d_in[9];
  const float* nw   = (const float*)d_in[10];

  char* ws = (char*)d_ws;
  float*          res   = (float*)(ws + 0);                  // 1 MB
  __hip_bfloat16* xcb   = (__hip_bfloat16*)(ws + 1048576);   // 1 MB
  float*          xcT   = (float*)(ws + 2097152);            // 2 MB
  float*          zT    = (float*)(ws + 4194304);            // 2 MB
  float*          dtgT  = (float*)(ws + 6291456);            // 2 MB
  float*          dblBC = (float*)(ws + 8388608);            // 64 KB
  __hip_bfloat16* y     = (__hip_bfloat16*)(ws + 8454144);   // 1 MB
  __hip_bfloat16* wib   = (__hip_bfloat16*)(ws + 10485760);  // 14 MB
  __hip_bfloat16* wxb   = (__hip_bfloat16*)(ws + 25165824);  // 896 KB
  __hip_bfloat16* wob   = (__hip_bfloat16*)(ws + 26083328);  // 7 MB
  __hip_bfloat16* wdtb  = (__hip_bfloat16*)(ws + 33423360);  // 448 KB

  k_cast_all<<<N4ALL / 256, 256, 0, stream>>>(Wi, Wx, Wo, Wdt, wib, wxb, wob, wdtb);
  k_transpose_in<<<1024, 256, 0, stream>>>(x, res);

  for (int L = 0; L < NLAYER; ++L) {
    k_front<<<256, 1024, 0, stream>>>(res, nw + L * DIM,
                                      wib + (size_t)L * 2048 * 512,
                                      (const float4*)cw + (size_t)L * DINNER,
                                      cb + L * DINNER, xcb, xcT, zT);
    k_xdt<<<32, 1024, 0, stream>>>(xcb, wxb + (size_t)L * 64 * 1024,
                                   wdtb + (size_t)L * 1024 * 32, bdt + L * DINNER,
                                   dblBC, dtgT);
    k_scan<<<256, 1024, 0, stream>>>(dblBC, dtgT, xcT, zT,
                                     Alog + (size_t)L * DINNER * 16, Dv + L * DINNER, y);
    k_outproj<<<256, 1024, 0, stream>>>(y, wob + (size_t)L * 512 * 1024, res);
  }
  k_transpose_out<<<1024, 256, 0, stream>>>(res, (float*)d_out);
}